// Round 1
// baseline (1173.576 us; speedup 1.0000x reference)
//
#include <hip/hip_runtime.h>
#include <hip/hip_bf16.h>

#define B_  4
#define N_  2048
#define E_  256
#define H_  8
#define D_  32
#define QT  16
#define KC  64

// ---------------- LayerNorm: one block (256 thr) per row of 256 ----------------
__global__ __launch_bounds__(256) void ln_kernel(const float* __restrict__ x,
                                                 const float* __restrict__ g,
                                                 const float* __restrict__ be,
                                                 float* __restrict__ out)
{
    long row = blockIdx.x;
    int t = threadIdx.x;
    float v = x[row * E_ + t];
    float s = v, s2 = v * v;
#pragma unroll
    for (int off = 32; off; off >>= 1) {
        s  += __shfl_xor(s,  off, 64);
        s2 += __shfl_xor(s2, off, 64);
    }
    __shared__ float rs[4], rs2[4];
    int w = t >> 6;
    if ((t & 63) == 0) { rs[w] = s; rs2[w] = s2; }
    __syncthreads();
    s  = rs[0] + rs[1] + rs[2] + rs[3];
    s2 = rs2[0] + rs2[1] + rs2[2] + rs2[3];
    float mu  = s * (1.0f / E_);
    float var = s2 * (1.0f / E_) - mu * mu;
    float rstd = rsqrtf(var + 1e-5f);
    out[row * E_ + t] = (v - mu) * rstd * g[t] + be[t];
}

// ---------------- Generic fp32 GEMM: C[M,256] = A[M,256] @ W[256,256] ----------
// optional bias[256], optional residual[M,256], optional relu (before residual)
__global__ __launch_bounds__(256) void gemm256(const float* __restrict__ A,
                                               const float* __restrict__ W,
                                               const float* __restrict__ bias,
                                               const float* __restrict__ resid,
                                               float* __restrict__ C,
                                               int relu)
{
    const int K = E_, NN = E_;
    __shared__ float As[16][68];  // [k][m] transposed
    __shared__ float Bs[16][68];  // [k][n]
    int tid = threadIdx.x;
    int tx = tid & 15, ty = tid >> 4;
    int m0 = blockIdx.x * 64, n0 = blockIdx.y * 64;
    float acc[4][4] = {};

    for (int kb = 0; kb < K; kb += 16) {
        __syncthreads();
        {   // A tile 64x16 -> As[k][m]
            int am = tid >> 2;
            int ak = (tid & 3) << 2;
            float4 a4 = *(const float4*)&A[(long)(m0 + am) * K + kb + ak];
            As[ak + 0][am] = a4.x; As[ak + 1][am] = a4.y;
            As[ak + 2][am] = a4.z; As[ak + 3][am] = a4.w;
        }
        {   // B tile 16x64
            int br = tid >> 4;
            int bc = (tid & 15) << 2;
            *(float4*)&Bs[br][bc] = *(const float4*)&W[(long)(kb + br) * NN + n0 + bc];
        }
        __syncthreads();
#pragma unroll
        for (int kk = 0; kk < 16; kk++) {
            float4 a4 = *(float4*)&As[kk][ty * 4];
            float4 b4 = *(float4*)&Bs[kk][tx * 4];
            float a[4] = {a4.x, a4.y, a4.z, a4.w};
            float b[4] = {b4.x, b4.y, b4.z, b4.w};
#pragma unroll
            for (int i = 0; i < 4; i++)
#pragma unroll
                for (int j = 0; j < 4; j++)
                    acc[i][j] += a[i] * b[j];
        }
    }
#pragma unroll
    for (int i = 0; i < 4; i++) {
        int m = m0 + ty * 4 + i;
        int n = n0 + tx * 4;
        float4 o = make_float4(acc[i][0], acc[i][1], acc[i][2], acc[i][3]);
        if (bias) {
            o.x += bias[n]; o.y += bias[n + 1]; o.z += bias[n + 2]; o.w += bias[n + 3];
        }
        if (relu) {
            o.x = fmaxf(o.x, 0.f); o.y = fmaxf(o.y, 0.f);
            o.z = fmaxf(o.z, 0.f); o.w = fmaxf(o.w, 0.f);
        }
        if (resid) {
            float4 rr = *(const float4*)&resid[(long)m * NN + n];
            o.x += rr.x; o.y += rr.y; o.z += rr.z; o.w += rr.w;
        }
        *(float4*)&C[(long)m * NN + n] = o;
    }
}

// ---------------- Fused influence attention (flash-style online softmax) -------
// scores = q.k/sqrt(D) + iw1*infl + ib1 ; w = softmax(scores) * (iw2*infl + ib2)
// out = w @ v.  Reweight folded into numerator: o = sum p*r*v, l = sum p, out=o/l
__global__ __launch_bounds__(256) void attn_kernel(const float* __restrict__ q,
                                                   const float* __restrict__ k,
                                                   const float* __restrict__ v,
                                                   const float* __restrict__ infl,
                                                   const float* __restrict__ iw1p,
                                                   const float* __restrict__ ib1p,
                                                   const float* __restrict__ iw2p,
                                                   const float* __restrict__ ib2p,
                                                   float* __restrict__ out)
{
    int blk = blockIdx.x;                 // B * (N/QT)
    int b   = blk / (N_ / QT);
    int q0  = (blk % (N_ / QT)) * QT;
    int tid = threadIdx.x;
    int r = tid >> 4, c = tid & 15;

    const float iw1 = iw1p[0], ib1 = ib1p[0], iw2 = iw2p[0], ib2 = ib2p[0];
    const float scale = 0.17677669529663687f;  // 1/sqrt(32)

    __shared__ float q_lds[QT][260];
    __shared__ float k_lds[KC][36];
    __shared__ float v_lds[KC][36];
    __shared__ float infl_lds[QT][68];
    __shared__ float pr_lds[QT][68];

    // load q tile: 16 rows x 256 cols (all heads)
#pragma unroll
    for (int i = 0; i < 4; i++) {
        int idx  = tid + i * 256;        // float4 index 0..1023
        int row  = idx >> 6;
        int col4 = (idx & 63) << 2;
        float4 t4 = *(const float4*)&q[((long)b * N_ + q0 + row) * E_ + col4];
        *(float4*)&q_lds[row][col4] = t4;
    }

    float  m_s[H_], l_s[H_];
    float2 o_s[H_];
#pragma unroll
    for (int h = 0; h < H_; h++) {
        m_s[h] = -1e30f; l_s[h] = 0.f; o_s[h] = make_float2(0.f, 0.f);
    }

    for (int k0 = 0; k0 < N_; k0 += KC) {
        __syncthreads();  // prior iteration fully done before overwriting infl
        {   // influence tile QT x KC
            int row  = tid >> 4;
            int col4 = (tid & 15) << 2;
            float4 t4 = *(const float4*)&infl[((long)b * N_ + q0 + row) * N_ + k0 + col4];
            *(float4*)&infl_lds[row][col4] = t4;
        }
#pragma unroll
        for (int h = 0; h < H_; h++) {
            __syncthreads();   // previous head's reads done; infl visible (h==0)
            {   // k,v chunk: 64 rows x 32 cols, 2 float4 per thread each
                int kk = tid >> 3;
                int dd = (tid & 7) << 2;
                long base = ((long)b * N_ + k0 + kk) * E_ + h * D_ + dd;
                *(float4*)&k_lds[kk][dd]      = *(const float4*)&k[base];
                *(float4*)&v_lds[kk][dd]      = *(const float4*)&v[base];
                *(float4*)&k_lds[kk + 32][dd] = *(const float4*)&k[base + 32L * E_];
                *(float4*)&v_lds[kk + 32][dd] = *(const float4*)&v[base + 32L * E_];
            }
            __syncthreads();

            // scores for k = c + 16j
            float acc4[4] = {0.f, 0.f, 0.f, 0.f};
#pragma unroll
            for (int d = 0; d < D_; d += 4) {
                float4 qv = *(float4*)&q_lds[r][h * D_ + d];
#pragma unroll
                for (int j = 0; j < 4; j++) {
                    float4 kv = *(float4*)&k_lds[c + 16 * j][d];
                    acc4[j] += qv.x * kv.x + qv.y * kv.y + qv.z * kv.z + qv.w * kv.w;
                }
            }
            float s[4];
#pragma unroll
            for (int j = 0; j < 4; j++)
                s[j] = acc4[j] * scale + iw1 * infl_lds[r][c + 16 * j] + ib1;

            float mc = fmaxf(fmaxf(s[0], s[1]), fmaxf(s[2], s[3]));
#pragma unroll
            for (int off = 8; off; off >>= 1)
                mc = fmaxf(mc, __shfl_xor(mc, off, 16));
            float m_new = fmaxf(m_s[h], mc);
            float resc  = __expf(m_s[h] - m_new);

            float psum = 0.f;
            float pr[4];
#pragma unroll
            for (int j = 0; j < 4; j++) {
                float p = __expf(s[j] - m_new);
                psum += p;
                pr[j] = p * (iw2 * infl_lds[r][c + 16 * j] + ib2);
            }
#pragma unroll
            for (int off = 8; off; off >>= 1)
                psum += __shfl_xor(psum, off, 16);
            l_s[h] = l_s[h] * resc + psum;
            m_s[h] = m_new;

            // stage pr; row's 16 threads are in the same wave -> wave-synchronous
#pragma unroll
            for (int j = 0; j < 4; j++) pr_lds[r][c + 16 * j] = pr[j];

            float2 o = o_s[h];
            o.x *= resc; o.y *= resc;
            int d0 = c * 2;
#pragma unroll
            for (int kk = 0; kk < KC; kk++) {
                float  p  = pr_lds[r][kk];
                float2 vv = *(float2*)&v_lds[kk][d0];
                o.x += p * vv.x;
                o.y += p * vv.y;
            }
            o_s[h] = o;
        }
    }

#pragma unroll
    for (int h = 0; h < H_; h++) {
        float inv = 1.0f / l_s[h];
        float2 o = o_s[h];
        o.x *= inv; o.y *= inv;
        *(float2*)&out[((long)b * N_ + q0 + r) * E_ + h * D_ + c * 2] = o;
    }
}

// ------------------------------- launch ---------------------------------------
extern "C" void kernel_launch(void* const* d_in, const int* in_sizes, int n_in,
                              void* d_out, int out_size, void* d_ws, size_t ws_size,
                              hipStream_t stream)
{
    (void)in_sizes; (void)n_in; (void)out_size; (void)ws_size;
    const float* x    = (const float*)d_in[0];
    const float* infl = (const float*)d_in[1];
    const float* Wq   = (const float*)d_in[2];
    const float* Wk   = (const float*)d_in[3];
    const float* Wv   = (const float*)d_in[4];
    const float* Wo   = (const float*)d_in[5];
    const float* bo   = (const float*)d_in[6];
    const float* iw1  = (const float*)d_in[7];
    const float* ib1  = (const float*)d_in[8];
    const float* iw2  = (const float*)d_in[9];
    const float* ib2  = (const float*)d_in[10];
    const float* W1   = (const float*)d_in[11];
    const float* b1   = (const float*)d_in[12];
    const float* W2   = (const float*)d_in[13];
    const float* b2   = (const float*)d_in[14];
    const float* g1   = (const float*)d_in[15];
    const float* be1  = (const float*)d_in[16];
    const float* g2   = (const float*)d_in[17];
    const float* be2  = (const float*)d_in[18];

    float* ws = (float*)d_ws;
    const long SZ = (long)B_ * N_ * E_;      // 2,097,152 floats = 8 MB
    float* ln   = ws;                        // ln1; reused as attn output
    float* qb   = ws + SZ;                   // q;  reused as ln2
    float* kb   = ws + 2 * SZ;               // k;  reused as ffn hidden t
    float* vb   = ws + 3 * SZ;               // v
    float* hb   = ws + 4 * SZ;               // h = attn@Wo + bo + x
    float* attn = ln;

    dim3 gg(E_ * (long)B_ * N_ / E_ / 64, E_ / 64);  // (128, 4)
    dim3 gemm_grid((B_ * N_) / 64, E_ / 64);
    (void)gg;

    // 1. ln1 = LN(x)
    ln_kernel<<<B_ * N_, 256, 0, stream>>>(x, g1, be1, ln);
    // 2. q,k,v
    gemm256<<<gemm_grid, 256, 0, stream>>>(ln, Wq, nullptr, nullptr, qb, 0);
    gemm256<<<gemm_grid, 256, 0, stream>>>(ln, Wk, nullptr, nullptr, kb, 0);
    gemm256<<<gemm_grid, 256, 0, stream>>>(ln, Wv, nullptr, nullptr, vb, 0);
    // 3. attention (writes into attn == ln buffer)
    attn_kernel<<<B_ * (N_ / QT), 256, 0, stream>>>(qb, kb, vb, infl,
                                                    iw1, ib1, iw2, ib2, attn);
    // 4. h = attn @ Wo + bo + x
    gemm256<<<gemm_grid, 256, 0, stream>>>(attn, Wo, bo, x, hb, 0);
    // 5. ln2 = LN(h) (into qb)
    ln_kernel<<<B_ * N_, 256, 0, stream>>>(hb, g2, be2, qb);
    // 6. t = relu(ln2 @ W1 + b1) (into kb)
    gemm256<<<gemm_grid, 256, 0, stream>>>(qb, W1, b1, nullptr, kb, 1);
    // 7. out = t @ W2 + b2 + h
    gemm256<<<gemm_grid, 256, 0, stream>>>(kb, W2, b2, hb, (float*)d_out, 0);
}

// Round 2
// 264.668 us; speedup vs baseline: 4.4341x; 4.4341x over previous
//
#include <hip/hip_runtime.h>
#include <hip/hip_bf16.h>

#define B_  4
#define N_  2048
#define E_  256
#define H_  8
#define D_  32
#define QT  16
#define KC  64
#define VTP 72   // V^T row stride (ushorts): 144B, 16B-aligned, bank-spread
#define PP  72   // P row stride (ushorts)

typedef __attribute__((ext_vector_type(8))) short bfx8;
typedef __attribute__((ext_vector_type(4))) float fx4;

__device__ __forceinline__ unsigned short f2bf(float f) {
    unsigned int u = __float_as_uint(f);
    u += 0x7fffu + ((u >> 16) & 1u);   // round-to-nearest-even
    return (unsigned short)(u >> 16);
}

// ---------------- LayerNorm: one block (256 thr) per row of 256 ----------------
__global__ __launch_bounds__(256) void ln_kernel(const float* __restrict__ x,
                                                 const float* __restrict__ g,
                                                 const float* __restrict__ be,
                                                 float* __restrict__ out)
{
    long row = blockIdx.x;
    int t = threadIdx.x;
    float v = x[row * E_ + t];
    float s = v, s2 = v * v;
#pragma unroll
    for (int off = 32; off; off >>= 1) {
        s  += __shfl_xor(s,  off, 64);
        s2 += __shfl_xor(s2, off, 64);
    }
    __shared__ float rs[4], rs2[4];
    int w = t >> 6;
    if ((t & 63) == 0) { rs[w] = s; rs2[w] = s2; }
    __syncthreads();
    s  = rs[0] + rs[1] + rs[2] + rs[3];
    s2 = rs2[0] + rs2[1] + rs2[2] + rs2[3];
    float mu  = s * (1.0f / E_);
    float var = s2 * (1.0f / E_) - mu * mu;
    float rstd = rsqrtf(var + 1e-5f);
    out[row * E_ + t] = (v - mu) * rstd * g[t] + be[t];
}

// ---------------- Generic fp32 GEMM: C[M,256] = A[M,256] @ W[256,256] ----------
// optional bias[256], optional residual[M,256], optional relu (before residual)
// out_bf16: write C as bf16 (for QKV)
__global__ __launch_bounds__(256) void gemm256(const float* __restrict__ A,
                                               const float* __restrict__ W,
                                               const float* __restrict__ bias,
                                               const float* __restrict__ resid,
                                               void* __restrict__ Cv,
                                               int relu, int out_bf16)
{
    const int K = E_, NN = E_;
    __shared__ float As[16][68];  // [k][m] transposed
    __shared__ float Bs[16][68];  // [k][n]
    int tid = threadIdx.x;
    int tx = tid & 15, ty = tid >> 4;
    int m0 = blockIdx.x * 64, n0 = blockIdx.y * 64;
    float acc[4][4] = {};

    for (int kb = 0; kb < K; kb += 16) {
        __syncthreads();
        {   // A tile 64x16 -> As[k][m]
            int am = tid >> 2;
            int ak = (tid & 3) << 2;
            float4 a4 = *(const float4*)&A[(long)(m0 + am) * K + kb + ak];
            As[ak + 0][am] = a4.x; As[ak + 1][am] = a4.y;
            As[ak + 2][am] = a4.z; As[ak + 3][am] = a4.w;
        }
        {   // B tile 16x64
            int br = tid >> 4;
            int bc = (tid & 15) << 2;
            *(float4*)&Bs[br][bc] = *(const float4*)&W[(long)(kb + br) * NN + n0 + bc];
        }
        __syncthreads();
#pragma unroll
        for (int kk = 0; kk < 16; kk++) {
            float4 a4 = *(float4*)&As[kk][ty * 4];
            float4 b4 = *(float4*)&Bs[kk][tx * 4];
            float a[4] = {a4.x, a4.y, a4.z, a4.w};
            float b[4] = {b4.x, b4.y, b4.z, b4.w};
#pragma unroll
            for (int i = 0; i < 4; i++)
#pragma unroll
                for (int j = 0; j < 4; j++)
                    acc[i][j] += a[i] * b[j];
        }
    }
#pragma unroll
    for (int i = 0; i < 4; i++) {
        int m = m0 + ty * 4 + i;
        int n = n0 + tx * 4;
        float4 o = make_float4(acc[i][0], acc[i][1], acc[i][2], acc[i][3]);
        if (bias) {
            o.x += bias[n]; o.y += bias[n + 1]; o.z += bias[n + 2]; o.w += bias[n + 3];
        }
        if (relu) {
            o.x = fmaxf(o.x, 0.f); o.y = fmaxf(o.y, 0.f);
            o.z = fmaxf(o.z, 0.f); o.w = fmaxf(o.w, 0.f);
        }
        if (resid) {
            float4 rr = *(const float4*)&resid[(long)m * NN + n];
            o.x += rr.x; o.y += rr.y; o.z += rr.z; o.w += rr.w;
        }
        if (out_bf16) {
            ushort4 u;
            u.x = f2bf(o.x); u.y = f2bf(o.y); u.z = f2bf(o.z); u.w = f2bf(o.w);
            *(ushort4*)&((unsigned short*)Cv)[(long)m * NN + n] = u;
        } else {
            *(float4*)&((float*)Cv)[(long)m * NN + n] = o;
        }
    }
}

// ---------------- MFMA flash attention with influence bias/reweight ------------
// scores = qk/sqrt(D) + iw1*infl + ib1 ; w = softmax(scores) * (iw2*infl + ib2)
// out = w @ v. Reweight in numerator: o = sum p*rw*v, l = sum p, out = o/l.
// Block: one (b, 16-q-row tile); 8 waves, wave w = head w. Influence tile loaded
// once per chunk (shared across heads); K/V/P traffic is wave-private.
__global__ __launch_bounds__(512, 4) void attn_mfma(
    const unsigned short* __restrict__ q,
    const unsigned short* __restrict__ k,
    const unsigned short* __restrict__ v,
    const float* __restrict__ infl,
    const float* __restrict__ iw1p, const float* __restrict__ ib1p,
    const float* __restrict__ iw2p, const float* __restrict__ ib2p,
    float* __restrict__ out)
{
    const int b   = blockIdx.x / (N_ / QT);
    const int q0  = (blockIdx.x % (N_ / QT)) * QT;
    const int tid = threadIdx.x;
    const int h    = tid >> 6;      // wave id = head
    const int lane = tid & 63;
    const int c = lane & 15, g = lane >> 4;

    const float iw1 = iw1p[0], ib1 = ib1p[0], iw2 = iw2p[0], ib2 = ib2p[0];
    const float scale = 0.17677669529663687f;  // 1/sqrt(32)

    __shared__ float infl_lds[QT][68];                  // 4352 B (shared)
    __shared__ unsigned short vt_lds[H_][D_][VTP];      // 36864 B (wave-private slices)
    __shared__ unsigned short p_lds[H_][QT][PP];        // 18432 B (wave-private slices)

    // Q A-fragment: lane holds Q[q0 + c][hd + g*8 .. +7] (contiguous bf16x8)
    bfx8 qf = *(const bfx8*)&q[((long)(b * N_ + q0 + c)) * E_ + h * D_ + g * 8];

    fx4 o0 = {0.f, 0.f, 0.f, 0.f};
    fx4 o1 = {0.f, 0.f, 0.f, 0.f};
    float m_s[4] = {-1e30f, -1e30f, -1e30f, -1e30f};
    float l_s[4] = {0.f, 0.f, 0.f, 0.f};
    const fx4 zero = {0.f, 0.f, 0.f, 0.f};

    for (int k0 = 0; k0 < N_; k0 += KC) {
        __syncthreads();   // all waves done reading previous influence tile
        {   // cooperative influence tile load: 16 x 64 fp32, float2/thread
            int row = tid >> 5, col2 = (tid & 31) * 2;
            *(float2*)&infl_lds[row][col2] =
                *(const float2*)&infl[((long)(b * N_ + q0 + row)) * N_ + k0 + col2];
        }
        __syncthreads();

        // this lane's influence values (C-layout coords), reused for bias+reweight
        float fi[4][4];
#pragma unroll
        for (int t = 0; t < 4; t++)
#pragma unroll
            for (int r = 0; r < 4; r++)
                fi[t][r] = infl_lds[g * 4 + r][t * 16 + c];

        // QK^T: 4 key tiles, one MFMA each (K=32 == D)
        fx4 st[4];
#pragma unroll
        for (int t = 0; t < 4; t++) {
            bfx8 kf = *(const bfx8*)&k[((long)(b * N_ + k0 + t * 16 + c)) * E_ + h * D_ + g * 8];
            st[t] = __builtin_amdgcn_mfma_f32_16x16x32_bf16(qf, kf, zero, 0, 0, 0);
        }

        // stage V^T[d][key] for this head's chunk (packed-pair b32 writes, 2-way free)
        {
            int p2 = lane & 31, dh = (lane >> 5) * 16;
            const unsigned short* vs = &v[((long)(b * N_ + k0 + 2 * p2)) * E_ + h * D_ + dh];
            bfx8 va0 = *(const bfx8*)vs;
            bfx8 va1 = *(const bfx8*)(vs + 8);
            bfx8 vb0 = *(const bfx8*)(vs + E_);
            bfx8 vb1 = *(const bfx8*)(vs + E_ + 8);
            unsigned int* vtw = (unsigned int*)&vt_lds[h][0][0];
#pragma unroll
            for (int i = 0; i < 8; i++) {
                unsigned int val = (unsigned int)(unsigned short)va0[i] |
                                   ((unsigned int)(unsigned short)vb0[i] << 16);
                vtw[(dh + i) * (VTP / 2) + p2] = val;
            }
#pragma unroll
            for (int i = 0; i < 8; i++) {
                unsigned int val = (unsigned int)(unsigned short)va1[i] |
                                   ((unsigned int)(unsigned short)vb1[i] << 16);
                vtw[(dh + 8 + i) * (VTP / 2) + p2] = val;
            }
        }

        // scores + online softmax (wave-parallel, 16-lane-group reduce)
        float s[4][4];
#pragma unroll
        for (int t = 0; t < 4; t++)
#pragma unroll
            for (int r = 0; r < 4; r++)
                s[t][r] = st[t][r] * scale + iw1 * fi[t][r] + ib1;

#pragma unroll
        for (int r = 0; r < 4; r++) {
            float mc = fmaxf(fmaxf(s[0][r], s[1][r]), fmaxf(s[2][r], s[3][r]));
            mc = fmaxf(mc, __shfl_xor(mc, 1));
            mc = fmaxf(mc, __shfl_xor(mc, 2));
            mc = fmaxf(mc, __shfl_xor(mc, 4));
            mc = fmaxf(mc, __shfl_xor(mc, 8));
            float m_new = fmaxf(m_s[r], mc);
            float resc  = __expf(m_s[r] - m_new);
            float psum = 0.f;
#pragma unroll
            for (int t = 0; t < 4; t++) {
                float p = __expf(s[t][r] - m_new);
                s[t][r] = p;
                psum += p;
            }
            psum += __shfl_xor(psum, 1);
            psum += __shfl_xor(psum, 2);
            psum += __shfl_xor(psum, 4);
            psum += __shfl_xor(psum, 8);
            l_s[r] = l_s[r] * resc + psum;
            m_s[r] = m_new;
            o0[r] *= resc;
            o1[r] *= resc;
#pragma unroll
            for (int t = 0; t < 4; t++) {
                float pr = s[t][r] * (iw2 * fi[t][r] + ib2);
                p_lds[h][g * 4 + r][t * 16 + c] = f2bf(pr);
            }
        }

        // PV: O[16q][32d] += P[16q][64k] @ V[64k][32d]  (wave-private LDS, no barrier)
#pragma unroll
        for (int kh = 0; kh < 2; kh++) {
            bfx8 pf  = *(const bfx8*)&p_lds[h][c][g * 8 + kh * 32];
            bfx8 vf0 = *(const bfx8*)&vt_lds[h][c][g * 8 + kh * 32];
            bfx8 vf1 = *(const bfx8*)&vt_lds[h][16 + c][g * 8 + kh * 32];
            o0 = __builtin_amdgcn_mfma_f32_16x16x32_bf16(pf, vf0, o0, 0, 0, 0);
            o1 = __builtin_amdgcn_mfma_f32_16x16x32_bf16(pf, vf1, o1, 0, 0, 0);
        }
    }

#pragma unroll
    for (int r = 0; r < 4; r++) {
        float inv = 1.0f / l_s[r];
        long rowbase = ((long)(b * N_ + q0 + g * 4 + r)) * E_ + h * D_;
        out[rowbase + c]      = o0[r] * inv;
        out[rowbase + 16 + c] = o1[r] * inv;
    }
}

// ------------------------------- launch ---------------------------------------
extern "C" void kernel_launch(void* const* d_in, const int* in_sizes, int n_in,
                              void* d_out, int out_size, void* d_ws, size_t ws_size,
                              hipStream_t stream)
{
    (void)in_sizes; (void)n_in; (void)out_size; (void)ws_size;
    const float* x    = (const float*)d_in[0];
    const float* infl = (const float*)d_in[1];
    const float* Wq   = (const float*)d_in[2];
    const float* Wk   = (const float*)d_in[3];
    const float* Wv   = (const float*)d_in[4];
    const float* Wo   = (const float*)d_in[5];
    const float* bo   = (const float*)d_in[6];
    const float* iw1  = (const float*)d_in[7];
    const float* ib1  = (const float*)d_in[8];
    const float* iw2  = (const float*)d_in[9];
    const float* ib2  = (const float*)d_in[10];
    const float* W1   = (const float*)d_in[11];
    const float* b1   = (const float*)d_in[12];
    const float* W2   = (const float*)d_in[13];
    const float* b2   = (const float*)d_in[14];
    const float* g1   = (const float*)d_in[15];
    const float* be1  = (const float*)d_in[16];
    const float* g2   = (const float*)d_in[17];
    const float* be2  = (const float*)d_in[18];

    float* ws = (float*)d_ws;
    const long SZ = (long)B_ * N_ * E_;              // 2,097,152 elements
    float* ln = ws;                                   // 8MB: ln1 -> attn-out -> ln2
    float* hb = ws + SZ;                              // 8MB: h
    float* tb = ws + 2 * SZ;                          // 8MB: ffn hidden
    unsigned short* qb = (unsigned short*)(ws + 3 * SZ);  // 4MB bf16
    unsigned short* kb = qb + SZ;                     // 4MB bf16
    unsigned short* vb = kb + SZ;                     // 4MB bf16

    dim3 gemm_grid((B_ * N_) / 64, E_ / 64);

    // 1. ln1 = LN(x)
    ln_kernel<<<B_ * N_, 256, 0, stream>>>(x, g1, be1, ln);
    // 2. q,k,v (bf16 out)
    gemm256<<<gemm_grid, 256, 0, stream>>>(ln, Wq, nullptr, nullptr, qb, 0, 1);
    gemm256<<<gemm_grid, 256, 0, stream>>>(ln, Wk, nullptr, nullptr, kb, 0, 1);
    gemm256<<<gemm_grid, 256, 0, stream>>>(ln, Wv, nullptr, nullptr, vb, 0, 1);
    // 3. attention (writes fp32 into ln buffer)
    attn_mfma<<<B_ * (N_ / QT), 512, 0, stream>>>(qb, kb, vb, infl,
                                                  iw1, ib1, iw2, ib2, ln);
    // 4. h = attn @ Wo + bo + x
    gemm256<<<gemm_grid, 256, 0, stream>>>(ln, Wo, bo, x, hb, 0, 0);
    // 5. ln2 = LN(h)
    ln_kernel<<<B_ * N_, 256, 0, stream>>>(hb, g2, be2, ln);
    // 6. t = relu(ln2 @ W1 + b1)
    gemm256<<<gemm_grid, 256, 0, stream>>>(ln, W1, b1, nullptr, tb, 1, 0);
    // 7. out = t @ W2 + b2 + h
    gemm256<<<gemm_grid, 256, 0, stream>>>(tb, W2, b2, hb, (float*)d_out, 0, 0);
}

// Round 3
// 211.153 us; speedup vs baseline: 5.5579x; 1.2534x over previous
//
#include <hip/hip_runtime.h>
#include <hip/hip_bf16.h>

#define B_  4
#define N_  2048
#define E_  256
#define H_  8
#define D_  32
#define QT  16
#define KC  64
#define VTP 72   // V^T row stride (ushorts): 144B, 16B-aligned, 2-way banks (free)
#define PP  72   // P row stride (ushorts)
#define LOG2E 1.4426950408889634f

typedef __attribute__((ext_vector_type(8))) short bfx8;
typedef __attribute__((ext_vector_type(4))) float fx4;

__device__ __forceinline__ unsigned short f2bf(float f) {
    unsigned int u = __float_as_uint(f);
    u += 0x7fffu + ((u >> 16) & 1u);   // round-to-nearest-even
    return (unsigned short)(u >> 16);
}

// ---------- prep: Wt[n][k] = bf16(W[k][n]) for 6 weight matrices ----------
__global__ __launch_bounds__(256) void prep_w(
    const float* Wa, const float* Wb, const float* Wc,
    const float* Wd, const float* We, const float* Wf,
    unsigned short* Oa, unsigned short* Ob, unsigned short* Oc,
    unsigned short* Od, unsigned short* Oe, unsigned short* Of)
{
    int z = blockIdx.z;
    const float* src = z == 0 ? Wa : z == 1 ? Wb : z == 2 ? Wc
                     : z == 3 ? Wd : z == 4 ? We : Wf;
    unsigned short* dst = z == 0 ? Oa : z == 1 ? Ob : z == 2 ? Oc
                        : z == 3 ? Od : z == 4 ? Oe : Of;
    __shared__ float t[32][33];
    int n0 = blockIdx.x * 32, k0 = blockIdx.y * 32;
    int tx = threadIdx.x & 31, ty = threadIdx.x >> 5;
#pragma unroll
    for (int i = 0; i < 4; i++)
        t[ty + i * 8][tx] = src[(k0 + ty + i * 8) * E_ + n0 + tx];
    __syncthreads();
#pragma unroll
    for (int i = 0; i < 4; i++)
        dst[(n0 + ty + i * 8) * E_ + k0 + tx] = f2bf(t[tx][ty + i * 8]);
}

// ---------- LayerNorm: one block (256 thr) per row; bf16 out ----------
__global__ __launch_bounds__(256) void ln_kernel(const float* __restrict__ x,
                                                 const float* __restrict__ g,
                                                 const float* __restrict__ be,
                                                 unsigned short* __restrict__ out)
{
    long row = blockIdx.x;
    int t = threadIdx.x;
    float v = x[row * E_ + t];
    float s = v, s2 = v * v;
#pragma unroll
    for (int off = 32; off; off >>= 1) {
        s  += __shfl_xor(s,  off, 64);
        s2 += __shfl_xor(s2, off, 64);
    }
    __shared__ float rs[4], rs2[4];
    int w = t >> 6;
    if ((t & 63) == 0) { rs[w] = s; rs2[w] = s2; }
    __syncthreads();
    s  = rs[0] + rs[1] + rs[2] + rs[3];
    s2 = rs2[0] + rs2[1] + rs2[2] + rs2[3];
    float mu  = s * (1.0f / E_);
    float var = s2 * (1.0f / E_) - mu * mu;
    float rstd = rsqrtf(var + 1e-5f);
    out[row * E_ + t] = f2bf((v - mu) * rstd * g[t] + be[t]);
}

// ---------- bf16 MFMA GEMM: C[M,256] = A[M,256] @ Wt[n][k]^T ----------
// 64x64 tile, whole K strip in LDS (one barrier), 4 waves x (2x2) 16x16x32 frags
__global__ __launch_bounds__(256, 2) void gemm_mfma(
    const unsigned short* __restrict__ A,
    const unsigned short* __restrict__ Wt,
    const float* __restrict__ bias,
    const float* __restrict__ resid,
    void* __restrict__ Cv, int relu, int obf)
{
    __shared__ unsigned short As[64 * 264];
    __shared__ unsigned short Bs[64 * 264];
    int tid = threadIdx.x;
    int m0 = blockIdx.x * 64, n0 = blockIdx.y * 64;

    {   // stage both 64x256 strips (contiguous rows), coalesced 16B/lane
        const unsigned short* Ab = A  + (long)m0 * E_;
        const unsigned short* Bb = Wt + (long)n0 * E_;
        bfx8 va[8], vb[8];
#pragma unroll
        for (int i = 0; i < 8; i++) va[i] = *(const bfx8*)&Ab[(i * 256 + tid) * 8];
#pragma unroll
        for (int i = 0; i < 8; i++) vb[i] = *(const bfx8*)&Bb[(i * 256 + tid) * 8];
#pragma unroll
        for (int i = 0; i < 8; i++) {
            int fo = i * 256 + tid;
            int row = fo >> 5, c8 = fo & 31;
            *(bfx8*)&As[row * 264 + c8 * 8] = va[i];
            *(bfx8*)&Bs[row * 264 + c8 * 8] = vb[i];
        }
    }
    __syncthreads();

    int lane = tid & 63, w = tid >> 6;
    int c = lane & 15, g = lane >> 4;
    int wm = (w >> 1) * 32, wn = (w & 1) * 32;
    fx4 acc[2][2] = {};

#pragma unroll
    for (int ks = 0; ks < 8; ks++) {
        bfx8 a0 = *(const bfx8*)&As[(wm + c)      * 264 + ks * 32 + g * 8];
        bfx8 a1 = *(const bfx8*)&As[(wm + 16 + c) * 264 + ks * 32 + g * 8];
        bfx8 b0 = *(const bfx8*)&Bs[(wn + c)      * 264 + ks * 32 + g * 8];
        bfx8 b1 = *(const bfx8*)&Bs[(wn + 16 + c) * 264 + ks * 32 + g * 8];
        acc[0][0] = __builtin_amdgcn_mfma_f32_16x16x32_bf16(a0, b0, acc[0][0], 0, 0, 0);
        acc[0][1] = __builtin_amdgcn_mfma_f32_16x16x32_bf16(a0, b1, acc[0][1], 0, 0, 0);
        acc[1][0] = __builtin_amdgcn_mfma_f32_16x16x32_bf16(a1, b0, acc[1][0], 0, 0, 0);
        acc[1][1] = __builtin_amdgcn_mfma_f32_16x16x32_bf16(a1, b1, acc[1][1], 0, 0, 0);
    }

#pragma unroll
    for (int fm = 0; fm < 2; fm++)
#pragma unroll
        for (int r = 0; r < 4; r++) {
            int m = m0 + wm + fm * 16 + g * 4 + r;
#pragma unroll
            for (int fn = 0; fn < 2; fn++) {
                int n = n0 + wn + fn * 16 + c;
                float o = acc[fm][fn][r];
                if (bias)  o += bias[n];
                if (relu)  o = fmaxf(o, 0.f);
                if (resid) o += resid[(long)m * E_ + n];
                if (obf) ((unsigned short*)Cv)[(long)m * E_ + n] = f2bf(o);
                else     ((float*)Cv)[(long)m * E_ + n] = o;
            }
        }
}

// ---------- barrier-free MFMA flash attention with influence bias/reweight ----
// scores = qk/sqrt(D) + iw1*infl + ib1 ; w = softmax(scores) * (iw2*infl + ib2)
// o = sum p*rw*v, l = sum p, out = o/l.  log2-domain softmax (native v_exp_f32).
// 8 waves = 8 heads; influence read per-lane from global (L1/L2-hot);
// all LDS wave-private -> no __syncthreads at all.
__global__ __launch_bounds__(512, 4) void attn_mfma(
    const unsigned short* __restrict__ q,
    const unsigned short* __restrict__ k,
    const unsigned short* __restrict__ v,
    const float* __restrict__ infl,
    const float* __restrict__ iw1p, const float* __restrict__ ib1p,
    const float* __restrict__ iw2p, const float* __restrict__ ib2p,
    unsigned short* __restrict__ out)
{
    const int b   = blockIdx.x / (N_ / QT);
    const int q0  = (blockIdx.x % (N_ / QT)) * QT;
    const int tid = threadIdx.x;
    const int h    = tid >> 6;      // wave id = head
    const int lane = tid & 63;
    const int c = lane & 15, g = lane >> 4;

    const float iw1e = iw1p[0] * LOG2E, ib1e = ib1p[0] * LOG2E;
    const float iw2 = iw2p[0], ib2 = ib2p[0];
    const float scale2 = 0.17677669529663687f * LOG2E;  // log2e/sqrt(32)

    __shared__ unsigned short vt_lds[H_][D_][VTP];      // wave-private slices
    __shared__ unsigned short p_lds[H_][QT][PP];        // wave-private slices

    // Q A-fragment: lane holds Q[q0+c][h*32 + g*8 .. +7]
    bfx8 qf = *(const bfx8*)&q[((long)(b * N_ + q0 + c)) * E_ + h * D_ + g * 8];

    const float* fbase = &infl[((long)(b * N_ + q0 + g * 4)) * N_ + c];

    fx4 o0 = {0.f, 0.f, 0.f, 0.f};
    fx4 o1 = {0.f, 0.f, 0.f, 0.f};
    float m_s[4] = {-1e30f, -1e30f, -1e30f, -1e30f};
    float l_s[4] = {0.f, 0.f, 0.f, 0.f};
    const fx4 zero = {0.f, 0.f, 0.f, 0.f};

    for (int k0 = 0; k0 < N_; k0 += KC) {
        // influence per-lane direct loads (64B-segment coalesced, cache-hot)
        float fi[4][4];
#pragma unroll
        for (int t = 0; t < 4; t++)
#pragma unroll
            for (int r = 0; r < 4; r++)
                fi[t][r] = fbase[r * N_ + k0 + t * 16];

        // QK^T: 4 key tiles, one MFMA each (K=32 == D)
        fx4 st[4];
        __builtin_amdgcn_s_setprio(1);
#pragma unroll
        for (int t = 0; t < 4; t++) {
            bfx8 kf = *(const bfx8*)&k[((long)(b * N_ + k0 + t * 16 + c)) * E_ + h * D_ + g * 8];
            st[t] = __builtin_amdgcn_mfma_f32_16x16x32_bf16(qf, kf, zero, 0, 0, 0);
        }
        __builtin_amdgcn_s_setprio(0);

        // stage V^T[d][key] (packed-pair b32 writes; wave-private)
        {
            int p2 = lane & 31, dh = (lane >> 5) * 16;
            const unsigned short* vs = &v[((long)(b * N_ + k0 + 2 * p2)) * E_ + h * D_ + dh];
            bfx8 va0 = *(const bfx8*)vs;
            bfx8 va1 = *(const bfx8*)(vs + 8);
            bfx8 vb0 = *(const bfx8*)(vs + E_);
            bfx8 vb1 = *(const bfx8*)(vs + E_ + 8);
            unsigned int* vtw = (unsigned int*)&vt_lds[h][0][0];
#pragma unroll
            for (int i = 0; i < 8; i++) {
                unsigned int val = (unsigned int)(unsigned short)va0[i] |
                                   ((unsigned int)(unsigned short)vb0[i] << 16);
                vtw[(dh + i) * (VTP / 2) + p2] = val;
            }
#pragma unroll
            for (int i = 0; i < 8; i++) {
                unsigned int val = (unsigned int)(unsigned short)va1[i] |
                                   ((unsigned int)(unsigned short)vb1[i] << 16);
                vtw[(dh + 8 + i) * (VTP / 2) + p2] = val;
            }
        }

        // log2-domain scores + online softmax (wave-parallel 16-lane reduce)
        float s[4][4];
#pragma unroll
        for (int t = 0; t < 4; t++)
#pragma unroll
            for (int r = 0; r < 4; r++)
                s[t][r] = fmaf(st[t][r], scale2, fmaf(iw1e, fi[t][r], ib1e));

#pragma unroll
        for (int r = 0; r < 4; r++) {
            float mc = fmaxf(fmaxf(s[0][r], s[1][r]), fmaxf(s[2][r], s[3][r]));
            mc = fmaxf(mc, __shfl_xor(mc, 1));
            mc = fmaxf(mc, __shfl_xor(mc, 2));
            mc = fmaxf(mc, __shfl_xor(mc, 4));
            mc = fmaxf(mc, __shfl_xor(mc, 8));
            float m_new = fmaxf(m_s[r], mc);
            float resc  = __builtin_amdgcn_exp2f(m_s[r] - m_new);
            float p[4], psum = 0.f;
#pragma unroll
            for (int t = 0; t < 4; t++) {
                p[t] = __builtin_amdgcn_exp2f(s[t][r] - m_new);
                psum += p[t];
            }
            psum += __shfl_xor(psum, 1);
            psum += __shfl_xor(psum, 2);
            psum += __shfl_xor(psum, 4);
            psum += __shfl_xor(psum, 8);
            l_s[r] = l_s[r] * resc + psum;
            m_s[r] = m_new;
            o0[r] *= resc;
            o1[r] *= resc;
#pragma unroll
            for (int t = 0; t < 4; t++) {
                float pr = p[t] * fmaf(iw2, fi[t][r], ib2);
                p_lds[h][g * 4 + r][t * 16 + c] = f2bf(pr);
            }
        }

        // PV: O[16q][32d] += P[16q][64k] @ V[64k][32d]
        __builtin_amdgcn_s_setprio(1);
#pragma unroll
        for (int kh = 0; kh < 2; kh++) {
            bfx8 pf  = *(const bfx8*)&p_lds[h][c][g * 8 + kh * 32];
            bfx8 vf0 = *(const bfx8*)&vt_lds[h][c][g * 8 + kh * 32];
            bfx8 vf1 = *(const bfx8*)&vt_lds[h][16 + c][g * 8 + kh * 32];
            o0 = __builtin_amdgcn_mfma_f32_16x16x32_bf16(pf, vf0, o0, 0, 0, 0);
            o1 = __builtin_amdgcn_mfma_f32_16x16x32_bf16(pf, vf1, o1, 0, 0, 0);
        }
        __builtin_amdgcn_s_setprio(0);
    }

#pragma unroll
    for (int r = 0; r < 4; r++) {
        float inv = 1.0f / l_s[r];
        long rowbase = ((long)(b * N_ + q0 + g * 4 + r)) * E_ + h * D_;
        out[rowbase + c]      = f2bf(o0[r] * inv);
        out[rowbase + 16 + c] = f2bf(o1[r] * inv);
    }
}

// ------------------------------- launch ---------------------------------------
extern "C" void kernel_launch(void* const* d_in, const int* in_sizes, int n_in,
                              void* d_out, int out_size, void* d_ws, size_t ws_size,
                              hipStream_t stream)
{
    (void)in_sizes; (void)n_in; (void)out_size; (void)ws_size;
    const float* x    = (const float*)d_in[0];
    const float* infl = (const float*)d_in[1];
    const float* Wq   = (const float*)d_in[2];
    const float* Wk   = (const float*)d_in[3];
    const float* Wv   = (const float*)d_in[4];
    const float* Wo   = (const float*)d_in[5];
    const float* bo   = (const float*)d_in[6];
    const float* iw1  = (const float*)d_in[7];
    const float* ib1  = (const float*)d_in[8];
    const float* iw2  = (const float*)d_in[9];
    const float* ib2  = (const float*)d_in[10];
    const float* W1   = (const float*)d_in[11];
    const float* b1   = (const float*)d_in[12];
    const float* W2   = (const float*)d_in[13];
    const float* b2   = (const float*)d_in[14];
    const float* g1   = (const float*)d_in[15];
    const float* be1  = (const float*)d_in[16];
    const float* g2   = (const float*)d_in[17];
    const float* be2  = (const float*)d_in[18];

    char* base = (char*)d_ws;
    float*          hb  = (float*)base;                                   // 8 MB
    unsigned short* lnb = (unsigned short*)(base + (8  << 20));           // 4 MB
    unsigned short* qb  = (unsigned short*)(base + (12 << 20));           // 4 MB
    unsigned short* kb  = (unsigned short*)(base + (16 << 20));           // 4 MB
    unsigned short* vb  = (unsigned short*)(base + (20 << 20));           // 4 MB
    unsigned short* wqt = (unsigned short*)(base + (24 << 20));           // 6x128KB
    unsigned short* wkt = wqt + 65536;
    unsigned short* wvt = wkt + 65536;
    unsigned short* wot = wvt + 65536;
    unsigned short* w1t = wot + 65536;
    unsigned short* w2t = w1t + 65536;

    dim3 gemm_grid(128, 4);

    prep_w<<<dim3(8, 8, 6), 256, 0, stream>>>(Wq, Wk, Wv, Wo, W1, W2,
                                              wqt, wkt, wvt, wot, w1t, w2t);
    // 1. ln1 = LN(x) -> bf16
    ln_kernel<<<B_ * N_, 256, 0, stream>>>(x, g1, be1, lnb);
    // 2. q,k,v (bf16 MFMA GEMMs, bf16 out)
    gemm_mfma<<<gemm_grid, 256, 0, stream>>>(lnb, wqt, nullptr, nullptr, qb, 0, 1);
    gemm_mfma<<<gemm_grid, 256, 0, stream>>>(lnb, wkt, nullptr, nullptr, kb, 0, 1);
    gemm_mfma<<<gemm_grid, 256, 0, stream>>>(lnb, wvt, nullptr, nullptr, vb, 0, 1);
    // 3. attention (bf16 out into lnb)
    attn_mfma<<<B_ * (N_ / QT), 512, 0, stream>>>(qb, kb, vb, infl,
                                                  iw1, ib1, iw2, ib2, lnb);
    // 4. h = attn @ Wo + bo + x (fp32)
    gemm_mfma<<<gemm_grid, 256, 0, stream>>>(lnb, wot, bo, x, hb, 0, 0);
    // 5. ln2 = LN(h) -> bf16
    ln_kernel<<<B_ * N_, 256, 0, stream>>>(hb, g2, be2, lnb);
    // 6. t = relu(ln2 @ W1 + b1) -> bf16 (reuse qb)
    gemm_mfma<<<gemm_grid, 256, 0, stream>>>(lnb, w1t, b1, nullptr, qb, 1, 1);
    // 7. out = t @ W2 + b2 + h (fp32)
    gemm_mfma<<<gemm_grid, 256, 0, stream>>>(qb, w2t, b2, hb, (float*)d_out, 0, 0);
}